// Round 6
// baseline (353.980 us; speedup 1.0000x reference)
//
#include <hip/hip_runtime.h>
#include <cstdint>
#include <cstddef>

constexpr int CIN  = 16;
constexpr int COUT = 64;
constexpr int NMOM = 16 + 136;          // 16 sums + 136 upper-tri products
constexpr double BN_EPS = 1e-3;

typedef float v2f __attribute__((ext_vector_type(2)));
constexpr float INV_2PI = 0.15915494309189535f;

// prep layout (floats): A[64], B[64], c[64], Wc[16*64]
constexpr int P_A = 0, P_B = 64, P_C = 128, P_WC = 192, P_SZ = 192 + CIN * COUT;

constexpr int CHUNK = 512;              // scan chunk
constexpr int MB = 256;                 // moments blocks per input; 1 partial row/block

// ---------------- moments (both inputs, one launch) ------------------------
__global__ __launch_bounds__(256) void moments2_kernel(const float* __restrict__ xyz, int n1,
                                                       const float* __restrict__ feat, int n2,
                                                       float* __restrict__ partP,
                                                       float* __restrict__ partF)
{
    const int bb  = blockIdx.x;
    const bool second = (bb >= MB);
    const float* x = second ? feat : xyz;
    const int    n = second ? n2 : n1;
    float* part    = second ? partF : partP;
    const int blk  = second ? bb - MB : bb;

    float acc[NMOM];
#pragma unroll
    for (int i = 0; i < NMOM; i++) acc[i] = 0.f;

    int tid = blk * 256 + threadIdx.x;
    int stride = MB * 256;
    for (int r = tid; r < n; r += stride) {
        const float4* xp = (const float4*)(x + (size_t)r * CIN);
        float4 a0 = xp[0], a1 = xp[1], a2 = xp[2], a3 = xp[3];
        float v[16] = {a0.x,a0.y,a0.z,a0.w, a1.x,a1.y,a1.z,a1.w,
                       a2.x,a2.y,a2.z,a2.w, a3.x,a3.y,a3.z,a3.w};
#pragma unroll
        for (int i = 0; i < 16; i++) acc[i] += v[i];
        int c = 16;
#pragma unroll
        for (int k = 0; k < 16; k++)
#pragma unroll
            for (int l = k; l < 16; l++) { acc[c] = fmaf(v[k], v[l], acc[c]); c++; }
    }

    const int lane = threadIdx.x & 63;
    const int wid  = threadIdx.x >> 6;
    float r0 = 0.f, r1 = 0.f, r2 = 0.f;
#pragma unroll
    for (int i = 0; i < NMOM; i++) {
        float s = acc[i];
#pragma unroll
        for (int off = 1; off < 64; off <<= 1) s += __shfl_xor(s, off, 64);
        if (i < 64)       { if (lane == i)       r0 = s; }
        else if (i < 128) { if (lane == i - 64)  r1 = s; }
        else              { if (lane == i - 128) r2 = s; }
    }

    __shared__ float red[4][NMOM];
    red[wid][lane] = r0;
    red[wid][64 + lane] = r1;
    if (lane < NMOM - 128) red[wid][128 + lane] = r2;
    __syncthreads();
    int t = threadIdx.x;
    if (t < NMOM) {
        float s = red[0][t] + red[1][t] + red[2][t] + red[3][t];
        part[(size_t)blk * NMOM + t] = s;
    }
}

// ---------------- prep: fold BN analytically into the linears --------------
// gridDim.x == 2: block 0 = points branch, block 1 = feat branch.
__global__ __launch_bounds__(256) void prep_kernel(const float* __restrict__ Wpre, const float* __restrict__ bpre,
                            const float* __restrict__ gpre, const float* __restrict__ bepre,
                            const float* __restrict__ Wpos, const float* __restrict__ bpos,
                            const float* __restrict__ partP, const float* __restrict__ partF,
                            int nrows, int Np, int Vv,
                            float* __restrict__ prepP, float* __restrict__ prepF)
{
    const int t  = threadIdx.x;   // 0..255
    const int br = blockIdx.x;    // 0 or 1
    const float* part = br ? partF : partP;
    const double n    = br ? (double)Vv : (double)Np;
    const double inv_n = 1.0 / n;
    float* prep       = br ? prepF : prepP;

    __shared__ float sWpre[CIN * 64];    // 16x64
    __shared__ float sWpos[64 * 64];     // 64x64
    __shared__ double mom[NMOM];
    __shared__ double sS[64], sB[64];

    for (int i = t; i < CIN * 64; i += 256) sWpre[i] = Wpre[i];
    for (int i = t; i < 64 * 64; i += 256)  sWpos[i] = Wpos[i];

    if (t < NMOM) {
        double s0 = 0, s1 = 0, s2 = 0, s3 = 0, s4 = 0, s5 = 0, s6 = 0, s7 = 0;
        int r = 0;
        for (; r + 8 <= nrows; r += 8) {
            s0 += (double)part[(size_t)(r + 0) * NMOM + t];
            s1 += (double)part[(size_t)(r + 1) * NMOM + t];
            s2 += (double)part[(size_t)(r + 2) * NMOM + t];
            s3 += (double)part[(size_t)(r + 3) * NMOM + t];
            s4 += (double)part[(size_t)(r + 4) * NMOM + t];
            s5 += (double)part[(size_t)(r + 5) * NMOM + t];
            s6 += (double)part[(size_t)(r + 6) * NMOM + t];
            s7 += (double)part[(size_t)(r + 7) * NMOM + t];
        }
        for (; r < nrows; r++) s0 += (double)part[(size_t)r * NMOM + t];
        mom[t] = ((s0 + s1) + (s2 + s3)) + ((s4 + s5) + (s6 + s7));
    }
    __syncthreads();

    if (t < 64) {
        const int k = t;
        double mu[16];
#pragma unroll
        for (int i = 0; i < 16; i++) mu[i] = mom[i] * inv_n;
        double w[16];
#pragma unroll
        for (int i = 0; i < 16; i++) w[i] = (double)sWpre[i * 64 + k];

        double mk = (double)bpre[k];
#pragma unroll
        for (int i = 0; i < 16; i++) mk += mu[i] * w[i];

        double var = 0.0;
        int c = 16;
#pragma unroll
        for (int a = 0; a < 16; a++)
#pragma unroll
            for (int l = a; l < 16; l++) {
                double cov = mom[c] * inv_n - mu[a] * mu[l]; c++;
                var += (a == l ? 1.0 : 2.0) * w[a] * w[l] * cov;
            }

        double s_k = (double)gpre[k] / sqrt(var + BN_EPS);
        double B_k = (double)bepre[k] + s_k * ((double)bpre[k] - mk);
        sS[k] = s_k; sB[k] = B_k;
    }
    __syncthreads();

    if (t < 64) {
        const int k = t;
        double c0 = (double)bpos[k], c1 = 0.0;
        for (int j = 0; j < 64; j += 2) {
            c0 += sB[j]     * (double)sWpos[j * 64 + k];
            c1 += sB[j + 1] * (double)sWpos[(j + 1) * 64 + k];
        }
        prep[P_A + k] = (float)sS[k];
        prep[P_B + k] = (float)sB[k];
        prep[P_C + k] = (float)(c0 + c1);
    }

    {
        const int k  = t & 63;
        const int i0 = t >> 6;
        for (int i = i0; i < 16; i += 4) {
            double w0 = 0.0, w1 = 0.0;
            for (int j = 0; j < 64; j += 2) {
                w0 += (double)sWpre[i * 64 + j]     * sS[j]     * (double)sWpos[j * 64 + k];
                w1 += (double)sWpre[i * 64 + j + 1] * sS[j + 1] * (double)sWpos[(j + 1) * 64 + k];
            }
            prep[P_WC + i * 64 + k] = (float)(w0 + w1);
        }
    }
}

// ---------------- histogram of voxel ids -----------------------------------
__global__ __launch_bounds__(256) void hist_kernel(const int* __restrict__ unq, int n4,
                                                   int* __restrict__ cnt)
{
    int t = blockIdx.x * blockDim.x + threadIdx.x;
    int stride = gridDim.x * blockDim.x;
    const int4* u4 = (const int4*)unq;
    for (; t < n4; t += stride) {
        int4 u = u4[t];
        atomicAdd(cnt + u.x, 1);
        atomicAdd(cnt + u.y, 1);
        atomicAdd(cnt + u.z, 1);
        atomicAdd(cnt + u.w, 1);
    }
}

// ---------------- scan stage a: per-chunk sums ------------------------------
__global__ __launch_bounds__(256) void scan_a(const int* __restrict__ cnt, int V,
                                              int* __restrict__ chunkSum)
{
    const int b = blockIdx.x, t = threadIdx.x;
    int base = b * CHUNK;
    int i0 = base + t * 2, i1 = i0 + 1;
    int s = ((i0 < V) ? cnt[i0] : 0) + ((i1 < V) ? cnt[i1] : 0);
    __shared__ int red[4];
    const int lane = t & 63, wid = t >> 6;
#pragma unroll
    for (int off = 1; off < 64; off <<= 1) s += __shfl_xor(s, off, 64);
    if (lane == 0) red[wid] = s;
    __syncthreads();
    if (t == 0) chunkSum[b] = red[0] + red[1] + red[2] + red[3];
}

// ---------------- scan stage b: exclusive scan of chunk sums (<=256) --------
__global__ __launch_bounds__(256) void scan_b(const int* __restrict__ chunkSum, int nch,
                                              int* __restrict__ chunkBase,
                                              int* __restrict__ start, int V, int N)
{
    const int t = threadIdx.x;
    __shared__ int a[256];
    int v = (t < nch) ? chunkSum[t] : 0;
    a[t] = v;
    __syncthreads();
    for (int off = 1; off < 256; off <<= 1) {
        int add = (t >= off) ? a[t - off] : 0;
        __syncthreads();
        a[t] += add;
        __syncthreads();
    }
    chunkBase[t] = a[t] - v;   // exclusive
    if (t == 0) start[V] = N;
}

// ---------------- scan stage c: per-chunk exclusive scan -> start ----------
__global__ __launch_bounds__(64) void scan_c(const int* __restrict__ cnt, int V,
                                             const int* __restrict__ chunkBase,
                                             int* __restrict__ start)
{
    const int b = blockIdx.x;
    const int lane = threadIdx.x;
    const int base = b * CHUNK + lane * 8;
    int e[8];
    int run = 0;
#pragma unroll
    for (int j = 0; j < 8; j++) {
        int idx = base + j;
        int c = (idx < V) ? cnt[idx] : 0;
        e[j] = run;
        run += c;
    }
    int incl = run;
#pragma unroll
    for (int off = 1; off < 64; off <<= 1) {
        int vv = __shfl_up(incl, off, 64);
        if (lane >= off) incl += vv;
    }
    int excl = incl - run;
    int myBase = chunkBase[b] + excl;
#pragma unroll
    for (int j = 0; j < 8; j++) {
        int idx = base + j;
        if (idx < V) start[idx] = myBase + e[j];
    }
}

// ---------------- scatter: point indices into voxel-sorted order -----------
__global__ __launch_bounds__(256) void scatter_kernel(const int* __restrict__ unq, int N,
                                                      const int* __restrict__ start,
                                                      int* __restrict__ cursor,
                                                      int* __restrict__ sortedIdx)
{
    int t = blockIdx.x * blockDim.x + threadIdx.x;
    int stride = gridDim.x * blockDim.x;
    for (; t < N; t += stride) {
        int v = unq[t];
        int pos = start[v] + atomicAdd(cursor + v, 1);
        sortedIdx[pos] = t;
    }
}

// ---------------- fused voxel pass: packed math + branch-free inner --------
__global__ __launch_bounds__(256) void fused_pass(const float* __restrict__ xyz,
                                                  const float* __restrict__ feat,
                                                  const int* __restrict__ sortedIdx,
                                                  const int* __restrict__ start,
                                                  const float* __restrict__ Wpre,
                                                  const float* __restrict__ prepP,
                                                  const float* __restrict__ prepF,
                                                  float* __restrict__ outFinal,
                                                  float* __restrict__ statsPart, int V)
{
    const int lane = threadIdx.x & 63;
    const int wid  = threadIdx.x >> 6;

    v2f   wP[16];     // {wpre, wcP} interleaved -> v_pk_fma_f32
    float wcF[16];    // center dw weights (center is ~10% of work, scalar ok)
#pragma unroll
    for (int i = 0; i < 16; i++) {
        float wp = Wpre[i * 64 + lane];
        wP[i]  = (v2f){wp, prepP[P_WC + i * 64 + lane]};
        wcF[i] = prepF[P_WC + i * 64 + lane];
    }
    const float AP = prepP[P_A + lane], BP = prepP[P_B + lane], CP = prepP[P_C + lane];
    const float AF = prepF[P_A + lane], BF = prepF[P_B + lane], CF = prepF[P_C + lane];

    int wave = (blockIdx.x * blockDim.x + threadIdx.x) >> 6;
    int nw   = (gridDim.x * blockDim.x) >> 6;
    float s1 = 0.f, s2 = 0.f;

    for (int v = wave; v < V; v += nw) {
        const int sb    = start[v];
        const int total = start[v + 1] - sb;

        // issue center row load early; latency hides under point loop
        const float4* fp = (const float4*)(feat + (size_t)v * CIN);
        float4 f0 = fp[0], f1 = fp[1], f2 = fp[2], f3 = fp[3];

        v2f acc = (v2f){0.f, 0.f};     // {ssin, scos}

        auto point = [&](const float4& c0, const float4& c1,
                         const float4& c2, const float4& c3) {
            float xs[16] = {c0.x,c0.y,c0.z,c0.w, c1.x,c1.y,c1.z,c1.w,
                            c2.x,c2.y,c2.z,c2.w, c3.x,c3.y,c3.z,c3.w};
            v2f d = (v2f){0.f, 0.f};
#pragma unroll
            for (int i = 0; i < 16; i++) d += xs[i] * wP[i];
            float p  = fmaf(AP, d.x, BP);
            float r  = (d.y + CP) * INV_2PI;
            float sv = __builtin_amdgcn_sinf(r);
            float cv = __builtin_amdgcn_cosf(r);
            acc += p * (v2f){sv, cv};
        };

        for (int base = 0; base < total; base += 64) {
            const int m = min(64, total - base);
            int enc = (lane < m) ? sortedIdx[sb + base + lane] : 0;

            int pA = __shfl(enc, 0, 64);
            const float4* rp = (const float4*)(xyz + (size_t)pA * CIN);
            float4 a0 = rp[0], a1 = rp[1], a2 = rp[2], a3 = rp[3];

            int j = 0;
            for (; j + 2 <= m; j += 2) {
                int pB = __shfl(enc, j + 1, 64);
                const float4* rq = (const float4*)(xyz + (size_t)pB * CIN);
                float4 b0 = rq[0], b1 = rq[1], b2 = rq[2], b3 = rq[3];

                point(a0, a1, a2, a3);

                if (j + 2 < m) {
                    int pC = __shfl(enc, j + 2, 64);
                    const float4* rr = (const float4*)(xyz + (size_t)pC * CIN);
                    a0 = rr[0]; a1 = rr[1]; a2 = rr[2]; a3 = rr[3];
                }
                point(b0, b1, b2, b3);
            }
            if (j < m) point(a0, a1, a2, a3);
        }

        // center branch (scalar path)
        {
            float xs[16] = {f0.x,f0.y,f0.z,f0.w, f1.x,f1.y,f1.z,f1.w,
                            f2.x,f2.y,f2.z,f2.w, f3.x,f3.y,f3.z,f3.w};
            float dx = 0.f, dw = 0.f;
#pragma unroll
            for (int i = 0; i < 16; i++) {
                dx = fmaf(xs[i], wP[i].x, dx);
                dw = fmaf(xs[i], wcF[i],  dw);
            }
            float f  = fmaf(AF, dx, BF);
            float r  = (dw + CF) * INV_2PI;
            float sv = __builtin_amdgcn_sinf(r);
            float cv = __builtin_amdgcn_cosf(r);
            float cs = f * sv, cc = f * cv;
            float fin = fmaf(acc.x + cs, cs, (acc.y + cc) * cc);
            outFinal[(size_t)v * 64 + lane] = fin;
            s1 += fin;
            s2 = fmaf(fin, fin, s2);
        }
    }

    __shared__ float sh1[4][64], sh2[4][64];
    sh1[wid][lane] = s1; sh2[wid][lane] = s2;
    __syncthreads();
    if (threadIdx.x < 64) {
        float t1 = sh1[0][lane] + sh1[1][lane] + sh1[2][lane] + sh1[3][lane];
        float t2 = sh2[0][lane] + sh2[1][lane] + sh2[2][lane] + sh2[3][lane];
        float* row = statsPart + (size_t)(blockIdx.x & 63) * 128;
        atomicAdd(row + lane, t1);
        atomicAdd(row + 64 + lane, t2);
    }
}

// ---------------- final BN stats (reduce 64 statsPart rows) ----------------
__global__ void finalstats_kernel(const float* __restrict__ sp,
                                  const float* __restrict__ gn, const float* __restrict__ bnb,
                                  float* __restrict__ normP, int V)
{
    int t = threadIdx.x;  // 128 threads
    double s = 0.0;
#pragma unroll
    for (int r = 0; r < 64; r++) s += (double)sp[(size_t)r * 128 + t];
    __shared__ double red[128];
    red[t] = s;
    __syncthreads();
    if (t < 64) {
        double mean = red[t] / (double)V;
        double var  = red[64 + t] / (double)V - mean * mean;
        double ns   = (double)gn[t] / sqrt(var + BN_EPS);
        normP[t]      = (float)ns;
        normP[64 + t] = (float)((double)bnb[t] - ns * mean);
    }
}

// ---------------- normalize + relu (in place on d_out) ---------------------
__global__ __launch_bounds__(256) void norm_kernel(float* __restrict__ out,
                                                   const float* __restrict__ normP, size_t n4)
{
    size_t t = (size_t)blockIdx.x * blockDim.x + threadIdx.x;
    size_t stride = (size_t)gridDim.x * blockDim.x;
    const float4* ns4 = (const float4*)normP;
    const float4* nb4 = (const float4*)(normP + 64);
    float4* o4 = (float4*)out;
    for (; t < n4; t += stride) {
        int g = (int)(t & 15);
        float4 sc = ns4[g], bi = nb4[g];
        float4 v = o4[t];
        v.x = fmaxf(0.f, fmaf(sc.x, v.x, bi.x));
        v.y = fmaxf(0.f, fmaf(sc.y, v.y, bi.y));
        v.z = fmaxf(0.f, fmaf(sc.z, v.z, bi.z));
        v.w = fmaxf(0.f, fmaf(sc.w, v.w, bi.w));
        o4[t] = v;
    }
}

extern "C" void kernel_launch(void* const* d_in, const int* in_sizes, int n_in,
                              void* d_out, int out_size, void* d_ws, size_t ws_size,
                              hipStream_t stream)
{
    const float* feat  = (const float*)d_in[0];
    const float* xyz   = (const float*)d_in[1];
    const int*   unq   = (const int*)d_in[2];
    const float* Wpre  = (const float*)d_in[3];
    const float* bpre  = (const float*)d_in[4];
    const float* gpre  = (const float*)d_in[5];
    const float* bepre = (const float*)d_in[6];
    const float* Wpos  = (const float*)d_in[7];
    const float* bpos  = (const float*)d_in[8];
    const float* gn    = (const float*)d_in[9];
    const float* bnb   = (const float*)d_in[10];

    const int V = in_sizes[0] / CIN;
    const int N = in_sizes[1] / CIN;
    const int nch = (V + CHUNK - 1) / CHUNK;

    char* ws = (char*)d_ws;
    size_t off = 0;
    auto alloc = [&](size_t bytes) { void* p = ws + off; off += (bytes + 255) & ~size_t(255); return p; };

    // zeroed region first: cnt, cursor, statsPart (one memset)
    int*   cnt       = (int*)alloc((size_t)V * 4);
    int*   cursor    = (int*)alloc((size_t)V * 4);
    float* statsPart = (float*)alloc(64 * 128 * 4);
    const size_t zeroBytes = off;

    int*   start     = (int*)alloc((size_t)(V + 1) * 4);
    int*   chunkSum  = (int*)alloc(256 * 4);
    int*   chunkBase = (int*)alloc(256 * 4);
    int*   sortedIdx = (int*)alloc((size_t)N * 4);

    float* partP = (float*)alloc((size_t)MB * NMOM * 4);
    float* partF = (float*)alloc((size_t)MB * NMOM * 4);
    float* prepP = (float*)alloc(P_SZ * 4);
    float* prepF = (float*)alloc(P_SZ * 4);
    float* normP = (float*)alloc(128 * 4);

    hipMemsetAsync(d_ws, 0, zeroBytes, stream);

    hist_kernel<<<1024, 256, 0, stream>>>(unq, N / 4, cnt);
    moments2_kernel<<<2 * MB, 256, 0, stream>>>(xyz, N, feat, V, partP, partF);
    scan_a<<<nch, 256, 0, stream>>>(cnt, V, chunkSum);
    scan_b<<<1, 256, 0, stream>>>(chunkSum, nch, chunkBase, start, V, N);
    scan_c<<<nch, 64, 0, stream>>>(cnt, V, chunkBase, start);
    scatter_kernel<<<1024, 256, 0, stream>>>(unq, N, start, cursor, sortedIdx);
    prep_kernel<<<2, 256, 0, stream>>>(Wpre, bpre, gpre, bepre, Wpos, bpos,
                                       partP, partF, MB, N, V, prepP, prepF);
    fused_pass<<<2048, 256, 0, stream>>>(xyz, feat, sortedIdx, start, Wpre,
                                         prepP, prepF, (float*)d_out, statsPart, V);
    finalstats_kernel<<<1, 128, 0, stream>>>(statsPart, gn, bnb, normP, V);
    norm_kernel<<<512, 256, 0, stream>>>((float*)d_out, normP, (size_t)out_size / 4);
}

// Round 7
// 316.129 us; speedup vs baseline: 1.1197x; 1.1197x over previous
//
#include <hip/hip_runtime.h>
#include <cstdint>
#include <cstddef>

constexpr int CIN  = 16;
constexpr int COUT = 64;
constexpr int NMOM = 16 + 136;          // 16 sums + 136 upper-tri products
constexpr double BN_EPS = 1e-3;

constexpr float INV_2PI = 0.15915494309189535f;

// prep layout (floats): A[64], B[64], c[64], Wc[16*64]
constexpr int P_A = 0, P_B = 64, P_C = 128, P_WC = 192, P_SZ = 192 + CIN * COUT;

constexpr int CHUNK = 512;              // scan chunk
constexpr int MB = 256;                 // moments blocks per input; 1 partial row/block

__device__ __forceinline__ float rdl(float x, int l) {
    return __int_as_float(__builtin_amdgcn_readlane(__float_as_int(x), l));
}

// ---------------- moments (both inputs, one launch) ------------------------
__global__ __launch_bounds__(256) void moments2_kernel(const float* __restrict__ xyz, int n1,
                                                       const float* __restrict__ feat, int n2,
                                                       float* __restrict__ partP,
                                                       float* __restrict__ partF)
{
    const int bb  = blockIdx.x;
    const bool second = (bb >= MB);
    const float* x = second ? feat : xyz;
    const int    n = second ? n2 : n1;
    float* part    = second ? partF : partP;
    const int blk  = second ? bb - MB : bb;

    float acc[NMOM];
#pragma unroll
    for (int i = 0; i < NMOM; i++) acc[i] = 0.f;

    int tid = blk * 256 + threadIdx.x;
    int stride = MB * 256;
    for (int r = tid; r < n; r += stride) {
        const float4* xp = (const float4*)(x + (size_t)r * CIN);
        float4 a0 = xp[0], a1 = xp[1], a2 = xp[2], a3 = xp[3];
        float v[16] = {a0.x,a0.y,a0.z,a0.w, a1.x,a1.y,a1.z,a1.w,
                       a2.x,a2.y,a2.z,a2.w, a3.x,a3.y,a3.z,a3.w};
#pragma unroll
        for (int i = 0; i < 16; i++) acc[i] += v[i];
        int c = 16;
#pragma unroll
        for (int k = 0; k < 16; k++)
#pragma unroll
            for (int l = k; l < 16; l++) { acc[c] = fmaf(v[k], v[l], acc[c]); c++; }
    }

    const int lane = threadIdx.x & 63;
    const int wid  = threadIdx.x >> 6;
    float r0 = 0.f, r1 = 0.f, r2 = 0.f;
#pragma unroll
    for (int i = 0; i < NMOM; i++) {
        float s = acc[i];
#pragma unroll
        for (int off = 1; off < 64; off <<= 1) s += __shfl_xor(s, off, 64);
        if (i < 64)       { if (lane == i)       r0 = s; }
        else if (i < 128) { if (lane == i - 64)  r1 = s; }
        else              { if (lane == i - 128) r2 = s; }
    }

    __shared__ float red[4][NMOM];
    red[wid][lane] = r0;
    red[wid][64 + lane] = r1;
    if (lane < NMOM - 128) red[wid][128 + lane] = r2;
    __syncthreads();
    int t = threadIdx.x;
    if (t < NMOM) {
        float s = red[0][t] + red[1][t] + red[2][t] + red[3][t];
        part[(size_t)blk * NMOM + t] = s;
    }
}

// ---------------- prep: fold BN analytically into the linears --------------
__global__ __launch_bounds__(256) void prep_kernel(const float* __restrict__ Wpre, const float* __restrict__ bpre,
                            const float* __restrict__ gpre, const float* __restrict__ bepre,
                            const float* __restrict__ Wpos, const float* __restrict__ bpos,
                            const float* __restrict__ partP, const float* __restrict__ partF,
                            int nrows, int Np, int Vv,
                            float* __restrict__ prepP, float* __restrict__ prepF)
{
    const int t  = threadIdx.x;   // 0..255
    const int br = blockIdx.x;    // 0 or 1
    const float* part = br ? partF : partP;
    const double n    = br ? (double)Vv : (double)Np;
    const double inv_n = 1.0 / n;
    float* prep       = br ? prepF : prepP;

    __shared__ float sWpre[CIN * 64];    // 16x64
    __shared__ float sWpos[64 * 64];     // 64x64
    __shared__ double mom[NMOM];
    __shared__ double sS[64], sB[64];

    for (int i = t; i < CIN * 64; i += 256) sWpre[i] = Wpre[i];
    for (int i = t; i < 64 * 64; i += 256)  sWpos[i] = Wpos[i];

    if (t < NMOM) {
        double s0 = 0, s1 = 0, s2 = 0, s3 = 0, s4 = 0, s5 = 0, s6 = 0, s7 = 0;
        int r = 0;
        for (; r + 8 <= nrows; r += 8) {
            s0 += (double)part[(size_t)(r + 0) * NMOM + t];
            s1 += (double)part[(size_t)(r + 1) * NMOM + t];
            s2 += (double)part[(size_t)(r + 2) * NMOM + t];
            s3 += (double)part[(size_t)(r + 3) * NMOM + t];
            s4 += (double)part[(size_t)(r + 4) * NMOM + t];
            s5 += (double)part[(size_t)(r + 5) * NMOM + t];
            s6 += (double)part[(size_t)(r + 6) * NMOM + t];
            s7 += (double)part[(size_t)(r + 7) * NMOM + t];
        }
        for (; r < nrows; r++) s0 += (double)part[(size_t)r * NMOM + t];
        mom[t] = ((s0 + s1) + (s2 + s3)) + ((s4 + s5) + (s6 + s7));
    }
    __syncthreads();

    if (t < 64) {
        const int k = t;
        double mu[16];
#pragma unroll
        for (int i = 0; i < 16; i++) mu[i] = mom[i] * inv_n;
        double w[16];
#pragma unroll
        for (int i = 0; i < 16; i++) w[i] = (double)sWpre[i * 64 + k];

        double mk = (double)bpre[k];
#pragma unroll
        for (int i = 0; i < 16; i++) mk += mu[i] * w[i];

        double var = 0.0;
        int c = 16;
#pragma unroll
        for (int a = 0; a < 16; a++)
#pragma unroll
            for (int l = a; l < 16; l++) {
                double cov = mom[c] * inv_n - mu[a] * mu[l]; c++;
                var += (a == l ? 1.0 : 2.0) * w[a] * w[l] * cov;
            }

        double s_k = (double)gpre[k] / sqrt(var + BN_EPS);
        double B_k = (double)bepre[k] + s_k * ((double)bpre[k] - mk);
        sS[k] = s_k; sB[k] = B_k;
    }
    __syncthreads();

    if (t < 64) {
        const int k = t;
        double c0 = (double)bpos[k], c1 = 0.0;
        for (int j = 0; j < 64; j += 2) {
            c0 += sB[j]     * (double)sWpos[j * 64 + k];
            c1 += sB[j + 1] * (double)sWpos[(j + 1) * 64 + k];
        }
        prep[P_A + k] = (float)sS[k];
        prep[P_B + k] = (float)sB[k];
        prep[P_C + k] = (float)(c0 + c1);
    }

    {
        const int k  = t & 63;
        const int i0 = t >> 6;
        for (int i = i0; i < 16; i += 4) {
            double w0 = 0.0, w1 = 0.0;
            for (int j = 0; j < 64; j += 2) {
                w0 += (double)sWpre[i * 64 + j]     * sS[j]     * (double)sWpos[j * 64 + k];
                w1 += (double)sWpre[i * 64 + j + 1] * sS[j + 1] * (double)sWpos[(j + 1) * 64 + k];
            }
            prep[P_WC + i * 64 + k] = (float)(w0 + w1);
        }
    }
}

// ---------------- histogram of voxel ids -----------------------------------
__global__ __launch_bounds__(256) void hist_kernel(const int* __restrict__ unq, int n4,
                                                   int* __restrict__ cnt)
{
    int t = blockIdx.x * blockDim.x + threadIdx.x;
    int stride = gridDim.x * blockDim.x;
    const int4* u4 = (const int4*)unq;
    for (; t < n4; t += stride) {
        int4 u = u4[t];
        atomicAdd(cnt + u.x, 1);
        atomicAdd(cnt + u.y, 1);
        atomicAdd(cnt + u.z, 1);
        atomicAdd(cnt + u.w, 1);
    }
}

// ---------------- scan stage a: per-chunk sums ------------------------------
__global__ __launch_bounds__(256) void scan_a(const int* __restrict__ cnt, int V,
                                              int* __restrict__ chunkSum)
{
    const int b = blockIdx.x, t = threadIdx.x;
    int base = b * CHUNK;
    int i0 = base + t * 2, i1 = i0 + 1;
    int s = ((i0 < V) ? cnt[i0] : 0) + ((i1 < V) ? cnt[i1] : 0);
    __shared__ int red[4];
    const int lane = t & 63, wid = t >> 6;
#pragma unroll
    for (int off = 1; off < 64; off <<= 1) s += __shfl_xor(s, off, 64);
    if (lane == 0) red[wid] = s;
    __syncthreads();
    if (t == 0) chunkSum[b] = red[0] + red[1] + red[2] + red[3];
}

// ---------------- scan stage b: exclusive scan of chunk sums (<=256) --------
__global__ __launch_bounds__(256) void scan_b(const int* __restrict__ chunkSum, int nch,
                                              int* __restrict__ chunkBase,
                                              int* __restrict__ start, int V, int N)
{
    const int t = threadIdx.x;
    __shared__ int a[256];
    int v = (t < nch) ? chunkSum[t] : 0;
    a[t] = v;
    __syncthreads();
    for (int off = 1; off < 256; off <<= 1) {
        int add = (t >= off) ? a[t - off] : 0;
        __syncthreads();
        a[t] += add;
        __syncthreads();
    }
    chunkBase[t] = a[t] - v;   // exclusive
    if (t == 0) start[V] = N;
}

// ---------------- scan stage c: per-chunk exclusive scan -> start ----------
__global__ __launch_bounds__(64) void scan_c(const int* __restrict__ cnt, int V,
                                             const int* __restrict__ chunkBase,
                                             int* __restrict__ start)
{
    const int b = blockIdx.x;
    const int lane = threadIdx.x;
    const int base = b * CHUNK + lane * 8;
    int e[8];
    int run = 0;
#pragma unroll
    for (int j = 0; j < 8; j++) {
        int idx = base + j;
        int c = (idx < V) ? cnt[idx] : 0;
        e[j] = run;
        run += c;
    }
    int incl = run;
#pragma unroll
    for (int off = 1; off < 64; off <<= 1) {
        int vv = __shfl_up(incl, off, 64);
        if (lane >= off) incl += vv;
    }
    int excl = incl - run;
    int myBase = chunkBase[b] + excl;
#pragma unroll
    for (int j = 0; j < 8; j++) {
        int idx = base + j;
        if (idx < V) start[idx] = myBase + e[j];
    }
}

// ---------------- scatter: point indices into voxel-sorted order -----------
__global__ __launch_bounds__(256) void scatter_kernel(const int* __restrict__ unq, int N,
                                                      const int* __restrict__ start,
                                                      int* __restrict__ cursor,
                                                      int* __restrict__ sortedIdx)
{
    int t = blockIdx.x * blockDim.x + threadIdx.x;
    int stride = gridDim.x * blockDim.x;
    for (; t < N; t += stride) {
        int v = unq[t];
        int pos = start[v] + atomicAdd(cursor + v, 1);
        sortedIdx[pos] = t;
    }
}

// ---------------- fused voxel pass: cooperative gather + readlane ----------
// Lane l fetches quarter (l&3) of row-slot (l>>2); slot min(m,15) is the
// center (feat) row. Rows distributed at compute time via v_readlane.
// Voxel-level software pipeline: prefetch v+nw's index+row gather during
// compute of v.
__global__ __launch_bounds__(256) void fused_pass(const float* __restrict__ xyz,
                                                  const float* __restrict__ feat,
                                                  const int* __restrict__ sortedIdx,
                                                  const int* __restrict__ start,
                                                  const float* __restrict__ Wpre,
                                                  const float* __restrict__ prepP,
                                                  const float* __restrict__ prepF,
                                                  float* __restrict__ outFinal,
                                                  float* __restrict__ statsPart, int V)
{
    const int lane = threadIdx.x & 63;
    const int wid  = threadIdx.x >> 6;
    const int rq   = lane >> 2;      // row slot 0..15
    const int cc   = lane & 3;       // quarter within row

    float wpre[16], wcP[16];
#pragma unroll
    for (int i = 0; i < 16; i++) {
        wpre[i] = Wpre[i * 64 + lane];
        wcP[i]  = prepP[P_WC + i * 64 + lane];
    }
    const float AP = prepP[P_A + lane], BP = prepP[P_B + lane], CP = prepP[P_C + lane];
    const float AF = prepF[P_A + lane], BF = prepF[P_B + lane], CF = prepF[P_C + lane];

    const int wave = __builtin_amdgcn_readfirstlane((int)((blockIdx.x * blockDim.x + threadIdx.x) >> 6));
    const int nw   = (gridDim.x * blockDim.x) >> 6;
    float s1 = 0.f, s2 = 0.f;

    // prefetch: voxel bounds + cooperative 16-row (+center) gather
    auto prefetch = [&](int v, int& sb, int& m, float4& q) {
        sb = __builtin_amdgcn_readfirstlane(start[v]);
        int se = __builtin_amdgcn_readfirstlane(start[v + 1]);
        m = se - sb;
        int ms0 = min(m, 15);
        int row = min(rq, ms0);
        int ridx = sortedIdx[sb + row];           // padded array; garbage ok for row==ms0
        const float* bp = (row == ms0) ? (feat + (size_t)v * CIN)
                                       : (xyz  + (size_t)ridx * CIN);
        q = *(const float4*)(bp + cc * 4);
    };

    int v = wave;
    int sb = 0, m = 0; float4 q = {};
    if (v < V) prefetch(v, sb, m, q);

    while (v < V) {
        const int vn = v + nw;
        int sbn = 0, mn = 0; float4 qn = {};
        if (vn < V) prefetch(vn, sbn, mn, qn);

        float ssin = 0.f, scos = 0.f;
        const int ms0 = min(m, 15);

        auto pointmath = [&](const float4& qr, int j) {
            float dx = 0.f, dw = 0.f;
#pragma unroll
            for (int qq = 0; qq < 4; qq++) {
                const int src = 4 * j + qq;
                float x0 = rdl(qr.x, src), x1 = rdl(qr.y, src),
                      x2 = rdl(qr.z, src), x3 = rdl(qr.w, src);
                dx = fmaf(x0, wpre[4*qq+0], dx); dw = fmaf(x0, wcP[4*qq+0], dw);
                dx = fmaf(x1, wpre[4*qq+1], dx); dw = fmaf(x1, wcP[4*qq+1], dw);
                dx = fmaf(x2, wpre[4*qq+2], dx); dw = fmaf(x2, wcP[4*qq+2], dw);
                dx = fmaf(x3, wpre[4*qq+3], dx); dw = fmaf(x3, wcP[4*qq+3], dw);
            }
            float p  = fmaf(AP, dx, BP);
            float r  = (dw + CP) * INV_2PI;
            ssin = fmaf(p, __builtin_amdgcn_sinf(r), ssin);
            scos = fmaf(p, __builtin_amdgcn_cosf(r), scos);
        };

        for (int j = 0; j < ms0; j++) pointmath(q, j);

        // remainder rows for big voxels (m > 15), non-pipelined (rare)
        for (int base = 15; base < m; base += 16) {
            const int msr  = min(16, m - base);
            const int rowc = min(rq, msr - 1);
            int ridx = sortedIdx[sb + base + rowc];
            float4 qr = *(const float4*)(xyz + (size_t)ridx * CIN + cc * 4);
            for (int j = 0; j < msr; j++) pointmath(qr, j);
        }

        // center from slot ms0 (feat row), wcF reloaded (L1-resident)
        {
            float dx = 0.f, dw = 0.f;
            const int src0 = 4 * ms0;
#pragma unroll
            for (int qq = 0; qq < 4; qq++) {
                const int src = src0 + qq;
                float x0 = rdl(q.x, src), x1 = rdl(q.y, src),
                      x2 = rdl(q.z, src), x3 = rdl(q.w, src);
                const int i = 4 * qq;
                dx = fmaf(x0, wpre[i+0], dx); dw = fmaf(x0, prepF[P_WC + (i+0)*64 + lane], dw);
                dx = fmaf(x1, wpre[i+1], dx); dw = fmaf(x1, prepF[P_WC + (i+1)*64 + lane], dw);
                dx = fmaf(x2, wpre[i+2], dx); dw = fmaf(x2, prepF[P_WC + (i+2)*64 + lane], dw);
                dx = fmaf(x3, wpre[i+3], dx); dw = fmaf(x3, prepF[P_WC + (i+3)*64 + lane], dw);
            }
            float f  = fmaf(AF, dx, BF);
            float r  = (dw + CF) * INV_2PI;
            float sv = __builtin_amdgcn_sinf(r);
            float cv = __builtin_amdgcn_cosf(r);
            float cs = f * sv, ccn = f * cv;
            float fin = fmaf(ssin + cs, cs, (scos + ccn) * ccn);
            outFinal[(size_t)v * 64 + lane] = fin;
            s1 += fin;
            s2 = fmaf(fin, fin, s2);
        }

        v = vn; sb = sbn; m = mn; q = qn;
    }

    __shared__ float sh1[4][64], sh2[4][64];
    sh1[wid][lane] = s1; sh2[wid][lane] = s2;
    __syncthreads();
    if (threadIdx.x < 64) {
        float t1 = sh1[0][lane] + sh1[1][lane] + sh1[2][lane] + sh1[3][lane];
        float t2 = sh2[0][lane] + sh2[1][lane] + sh2[2][lane] + sh2[3][lane];
        float* row = statsPart + (size_t)(blockIdx.x & 63) * 128;
        atomicAdd(row + lane, t1);
        atomicAdd(row + 64 + lane, t2);
    }
}

// ---------------- final BN stats (reduce 64 statsPart rows) ----------------
__global__ void finalstats_kernel(const float* __restrict__ sp,
                                  const float* __restrict__ gn, const float* __restrict__ bnb,
                                  float* __restrict__ normP, int V)
{
    int t = threadIdx.x;  // 128 threads
    double s = 0.0;
#pragma unroll
    for (int r = 0; r < 64; r++) s += (double)sp[(size_t)r * 128 + t];
    __shared__ double red[128];
    red[t] = s;
    __syncthreads();
    if (t < 64) {
        double mean = red[t] / (double)V;
        double var  = red[64 + t] / (double)V - mean * mean;
        double ns   = (double)gn[t] / sqrt(var + BN_EPS);
        normP[t]      = (float)ns;
        normP[64 + t] = (float)((double)bnb[t] - ns * mean);
    }
}

// ---------------- normalize + relu (in place on d_out) ---------------------
__global__ __launch_bounds__(256) void norm_kernel(float* __restrict__ out,
                                                   const float* __restrict__ normP, size_t n4)
{
    size_t t = (size_t)blockIdx.x * blockDim.x + threadIdx.x;
    size_t stride = (size_t)gridDim.x * blockDim.x;
    const float4* ns4 = (const float4*)normP;
    const float4* nb4 = (const float4*)(normP + 64);
    float4* o4 = (float4*)out;
    for (; t < n4; t += stride) {
        int g = (int)(t & 15);
        float4 sc = ns4[g], bi = nb4[g];
        float4 v = o4[t];
        v.x = fmaxf(0.f, fmaf(sc.x, v.x, bi.x));
        v.y = fmaxf(0.f, fmaf(sc.y, v.y, bi.y));
        v.z = fmaxf(0.f, fmaf(sc.z, v.z, bi.z));
        v.w = fmaxf(0.f, fmaf(sc.w, v.w, bi.w));
        o4[t] = v;
    }
}

extern "C" void kernel_launch(void* const* d_in, const int* in_sizes, int n_in,
                              void* d_out, int out_size, void* d_ws, size_t ws_size,
                              hipStream_t stream)
{
    const float* feat  = (const float*)d_in[0];
    const float* xyz   = (const float*)d_in[1];
    const int*   unq   = (const int*)d_in[2];
    const float* Wpre  = (const float*)d_in[3];
    const float* bpre  = (const float*)d_in[4];
    const float* gpre  = (const float*)d_in[5];
    const float* bepre = (const float*)d_in[6];
    const float* Wpos  = (const float*)d_in[7];
    const float* bpos  = (const float*)d_in[8];
    const float* gn    = (const float*)d_in[9];
    const float* bnb   = (const float*)d_in[10];

    const int V = in_sizes[0] / CIN;
    const int N = in_sizes[1] / CIN;
    const int nch = (V + CHUNK - 1) / CHUNK;

    char* ws = (char*)d_ws;
    size_t off = 0;
    auto alloc = [&](size_t bytes) { void* p = ws + off; off += (bytes + 255) & ~size_t(255); return p; };

    // zeroed region first: cnt, cursor, statsPart (one memset)
    int*   cnt       = (int*)alloc((size_t)V * 4);
    int*   cursor    = (int*)alloc((size_t)V * 4);
    float* statsPart = (float*)alloc(64 * 128 * 4);
    const size_t zeroBytes = off;

    int*   start     = (int*)alloc((size_t)(V + 1) * 4);
    int*   chunkSum  = (int*)alloc(256 * 4);
    int*   chunkBase = (int*)alloc(256 * 4);
    int*   sortedIdx = (int*)alloc((size_t)(N + 64) * 4);   // +64 pad: fused_pass reads slot sb+row unconditionally

    float* partP = (float*)alloc((size_t)MB * NMOM * 4);
    float* partF = (float*)alloc((size_t)MB * NMOM * 4);
    float* prepP = (float*)alloc(P_SZ * 4);
    float* prepF = (float*)alloc(P_SZ * 4);
    float* normP = (float*)alloc(128 * 4);

    hipMemsetAsync(d_ws, 0, zeroBytes, stream);

    hist_kernel<<<1024, 256, 0, stream>>>(unq, N / 4, cnt);
    moments2_kernel<<<2 * MB, 256, 0, stream>>>(xyz, N, feat, V, partP, partF);
    scan_a<<<nch, 256, 0, stream>>>(cnt, V, chunkSum);
    scan_b<<<1, 256, 0, stream>>>(chunkSum, nch, chunkBase, start, V, N);
    scan_c<<<nch, 64, 0, stream>>>(cnt, V, chunkBase, start);
    scatter_kernel<<<1024, 256, 0, stream>>>(unq, N, start, cursor, sortedIdx);
    prep_kernel<<<2, 256, 0, stream>>>(Wpre, bpre, gpre, bepre, Wpos, bpos,
                                       partP, partF, MB, N, V, prepP, prepF);
    fused_pass<<<2048, 256, 0, stream>>>(xyz, feat, sortedIdx, start, Wpre,
                                         prepP, prepF, (float*)d_out, statsPart, V);
    finalstats_kernel<<<1, 128, 0, stream>>>(statsPart, gn, bnb, normP, V);
    norm_kernel<<<512, 256, 0, stream>>>((float*)d_out, normP, (size_t)out_size / 4);
}